// Round 1
// baseline (744.210 us; speedup 1.0000x reference)
//
#include <hip/hip_runtime.h>

#define NN 100000
#define NE 1600000
#define HF 128
#define NC 64
#define AP 136      // padded LDS row (bf16 elems): 272B row stride -> conflict-free b128 frag reads
#define NSB 49      // scan blocks: ceil(100000/2048)

typedef __bf16 bf16x8 __attribute__((ext_vector_type(8)));
typedef float  f32x4  __attribute__((ext_vector_type(4)));

__device__ __forceinline__ unsigned short f2b(float x) {
  unsigned int u = __float_as_uint(x);
  u += 0x7FFFu + ((u >> 16) & 1u);   // RNE
  return (unsigned short)(u >> 16);
}

// ---------------- weight prep: bf16 W^T + folded BN affine ----------------
__global__ void prep_weights(const float* __restrict__ conv_w, const float* __restrict__ conv_b,
                             const float* __restrict__ bn_g, const float* __restrict__ bn_b,
                             const float* __restrict__ bn_m, const float* __restrict__ bn_v,
                             const float* __restrict__ fc_w,
                             unsigned short* __restrict__ wt, unsigned short* __restrict__ wtf,
                             float* __restrict__ sarr, float* __restrict__ tarr) {
  int idx = blockIdx.x * 256 + threadIdx.x;
  if (idx < 6 * HF * HF) {
    int ls = idx / (HF * HF);
    int rem = idx - ls * HF * HF;
    int k = rem >> 7;          // input feature
    int n = rem & 127;         // output feature
    wt[(ls * HF + n) * HF + k] = f2b(conv_w[idx]);   // store W^T: [n][k]
  }
  if (idx < HF * NC) {
    int k = idx >> 6;
    int c = idx & 63;
    wtf[c * HF + k] = f2b(fc_w[idx]);                // fc W^T: [c][k]
  }
  if (idx < 6 * HF) {
    float s = bn_g[idx] * rsqrtf(bn_v[idx] + 1e-5f);
    sarr[idx] = s;
    tarr[idx] = (conv_b[idx] - bn_m[idx]) * s + bn_b[idx];  // fold linear bias into BN shift
  }
}

// ---------------- CSR build ----------------
__global__ void count_deg(const int* __restrict__ dst, int* __restrict__ cnt) {
  int e = blockIdx.x * 256 + threadIdx.x;
  if (e < NE) atomicAdd(&cnt[dst[e]], 1);
}

__global__ void scan_partial(const int* __restrict__ cnt, int* __restrict__ bsums) {
  __shared__ int sm[256];
  int base = blockIdx.x * 2048;
  int t = threadIdx.x;
  int s = 0;
  for (int j = 0; j < 8; j++) {
    int i = base + t * 8 + j;
    if (i < NN) s += cnt[i];
  }
  sm[t] = s; __syncthreads();
  for (int off = 128; off > 0; off >>= 1) {
    if (t < off) sm[t] += sm[t + off];
    __syncthreads();
  }
  if (t == 0) bsums[blockIdx.x] = sm[0];
}

__global__ void scan_bsums(int* __restrict__ bsums, int* __restrict__ offs) {
  if (threadIdx.x == 0) {
    int acc = 0;
    for (int i = 0; i < NSB; i++) { int v = bsums[i]; bsums[i] = acc; acc += v; }
    bsums[NSB] = acc;
    offs[NN] = acc;    // == NE
  }
}

__global__ void scan_write(const int* __restrict__ cnt, const int* __restrict__ bsums,
                           int* __restrict__ offs, int* __restrict__ cursor) {
  __shared__ int sm[256];
  int base = blockIdx.x * 2048;
  int t = threadIdx.x;
  int loc[8];
  int s = 0;
  for (int j = 0; j < 8; j++) {
    int i = base + t * 8 + j;
    int v = (i < NN) ? cnt[i] : 0;
    loc[j] = s; s += v;
  }
  sm[t] = s; __syncthreads();
  for (int off = 1; off < 256; off <<= 1) {
    int v2 = (t >= off) ? sm[t - off] : 0;
    __syncthreads();
    sm[t] += v2;
    __syncthreads();
  }
  int thread_excl = sm[t] - s;
  int b = bsums[blockIdx.x];
  for (int j = 0; j < 8; j++) {
    int i = base + t * 8 + j;
    if (i < NN) { int o = b + thread_excl + loc[j]; offs[i] = o; cursor[i] = o; }
  }
}

__global__ void scatter_edges(const int* __restrict__ src, const int* __restrict__ dst,
                              int* __restrict__ cursor, int* __restrict__ csr) {
  int e = blockIdx.x * 256 + threadIdx.x;
  if (e < NE) {
    int p = atomicAdd(&cursor[dst[e]], 1);
    csr[p] = src[e];
  }
}

// ---------------- aggregation: hsum[i] = h[i] + sum_{e->i} h[src_e] ----------------
__global__ __launch_bounds__(256) void aggregate(const float* __restrict__ h,
                                                 const int* __restrict__ offs,
                                                 const int* __restrict__ csr,
                                                 float* __restrict__ out) {
  int wave = threadIdx.x >> 6;
  int lane = threadIdx.x & 63;
  int node = blockIdx.x * 4 + wave;
  if (node >= NN) return;
  int beg = offs[node], end = offs[node + 1];
  float2 acc = *(const float2*)(h + (size_t)node * HF + lane * 2);
  for (int e = beg; e < end; e++) {
    int s = csr[e];
    float2 v = *(const float2*)(h + (size_t)s * HF + lane * 2);
    acc.x += v.x; acc.y += v.y;
  }
  *(float2*)(out + (size_t)node * HF + lane * 2) = acc;
}

// ---------------- fused 3x (Linear->BN->ReLU) via MFMA bf16 ----------------
__global__ __launch_bounds__(256) void mlp3(const float* __restrict__ in, float* __restrict__ out,
                                            const unsigned short* __restrict__ wt,
                                            const float* __restrict__ sarr, const float* __restrict__ tarr,
                                            int layer) {
  __shared__ unsigned short Ab[64 * AP];   // activation tile, bf16
  __shared__ unsigned short Wb[HF * AP];   // W^T tile, bf16
  int t = threadIdx.x;
  int lane = t & 63, wave = t >> 6;
  int row0 = blockIdx.x * 64;

  // stage input tile (fp32 -> bf16)
  for (int it = 0; it < 8; it++) {
    int idx = it * 256 + t;
    int r = idx >> 5;
    int c = (idx & 31) << 2;
    int gr = row0 + r;
    float4 v = make_float4(0.f, 0.f, 0.f, 0.f);
    if (gr < NN) v = *(const float4*)(in + (size_t)gr * HF + c);
    unsigned int lo = (unsigned int)f2b(v.x) | ((unsigned int)f2b(v.y) << 16);
    unsigned int hi = (unsigned int)f2b(v.z) | ((unsigned int)f2b(v.w) << 16);
    *(uint2*)&Ab[r * AP + c] = make_uint2(lo, hi);
  }

  int m = lane & 15, q = lane >> 4;
  const unsigned short* wbase = wt + layer * 3 * HF * HF;

  for (int sub = 0; sub < 3; sub++) {
    __syncthreads();                        // Ab ready / all readers of prev Wb done
    const unsigned short* wsub = wbase + sub * HF * HF;
    for (int it = 0; it < 16; it++) {
      int idx = it * 256 + t;
      int r = idx >> 5;
      int c = (idx & 31) << 2;
      *(uint2*)&Wb[r * AP + c] = *(const uint2*)(wsub + r * HF + c);
    }
    __syncthreads();                        // Wb ready

    bf16x8 af[4];
    #pragma unroll
    for (int k0 = 0; k0 < 4; k0++)
      af[k0] = *(const bf16x8*)&Ab[(wave * 16 + m) * AP + k0 * 32 + q * 8];

    f32x4 acc[8];
    #pragma unroll
    for (int nt = 0; nt < 8; nt++) {
      acc[nt] = (f32x4){0.f, 0.f, 0.f, 0.f};
      #pragma unroll
      for (int k0 = 0; k0 < 4; k0++) {
        bf16x8 bf = *(const bf16x8*)&Wb[(nt * 16 + m) * AP + k0 * 32 + q * 8];
        acc[nt] = __builtin_amdgcn_mfma_f32_16x16x32_bf16(af[k0], bf, acc[nt], 0, 0, 0);
      }
    }
    __syncthreads();                        // all MFMA reads of Ab done before overwrite

    const float* sp = sarr + (layer * 3 + sub) * HF;
    const float* tp = tarr + (layer * 3 + sub) * HF;
    #pragma unroll
    for (int nt = 0; nt < 8; nt++) {
      int c = nt * 16 + m;
      float sc = sp[c], sh = tp[c];
      #pragma unroll
      for (int i = 0; i < 4; i++) {
        int r = wave * 16 + q * 4 + i;     // C/D layout: col=lane&15, row=(lane>>4)*4+i
        float y = fmaxf(acc[nt][i] * sc + sh, 0.f);
        if (sub < 2) {
          Ab[r * AP + c] = f2b(y);
        } else {
          int gr = row0 + r;
          if (gr < NN) out[(size_t)gr * HF + c] = y;  // keep fp32 for next aggregation
        }
      }
    }
  }
}

// ---------------- FC (128->64) + log_softmax ----------------
__global__ __launch_bounds__(256) void fc_lsm(const float* __restrict__ h,
                                              const unsigned short* __restrict__ wtf,
                                              const float* __restrict__ fc_b,
                                              float* __restrict__ out) {
  __shared__ unsigned short Ab[64 * AP];
  __shared__ unsigned short Wb[NC * AP];
  __shared__ float Lb[64 * 69];            // pad 69: 5t+j bank pattern -> conflict-light
  __shared__ float smax[64], slog[64];
  int t = threadIdx.x;
  int lane = t & 63, wave = t >> 6;
  int row0 = blockIdx.x * 64;

  for (int it = 0; it < 8; it++) {
    int idx = it * 256 + t;
    int r = idx >> 5;
    int c = (idx & 31) << 2;
    int gr = row0 + r;
    float4 v = make_float4(0.f, 0.f, 0.f, 0.f);
    if (gr < NN) v = *(const float4*)(h + (size_t)gr * HF + c);
    unsigned int lo = (unsigned int)f2b(v.x) | ((unsigned int)f2b(v.y) << 16);
    unsigned int hi = (unsigned int)f2b(v.z) | ((unsigned int)f2b(v.w) << 16);
    *(uint2*)&Ab[r * AP + c] = make_uint2(lo, hi);
  }
  for (int it = 0; it < 8; it++) {
    int idx = it * 256 + t;                // 64 rows x 32 chunks
    int r = idx >> 5;
    int c = (idx & 31) << 2;
    *(uint2*)&Wb[r * AP + c] = *(const uint2*)(wtf + r * HF + c);
  }
  __syncthreads();

  int m = lane & 15, q = lane >> 4;
  bf16x8 af[4];
  #pragma unroll
  for (int k0 = 0; k0 < 4; k0++)
    af[k0] = *(const bf16x8*)&Ab[(wave * 16 + m) * AP + k0 * 32 + q * 8];

  f32x4 acc[4];
  #pragma unroll
  for (int nt = 0; nt < 4; nt++) {
    acc[nt] = (f32x4){0.f, 0.f, 0.f, 0.f};
    #pragma unroll
    for (int k0 = 0; k0 < 4; k0++) {
      bf16x8 bf = *(const bf16x8*)&Wb[(nt * 16 + m) * AP + k0 * 32 + q * 8];
      acc[nt] = __builtin_amdgcn_mfma_f32_16x16x32_bf16(af[k0], bf, acc[nt], 0, 0, 0);
    }
  }
  #pragma unroll
  for (int nt = 0; nt < 4; nt++) {
    int c = nt * 16 + m;
    float b = fc_b[c];
    #pragma unroll
    for (int i = 0; i < 4; i++)
      Lb[(wave * 16 + q * 4 + i) * 69 + c] = acc[nt][i] + b;
  }
  __syncthreads();

  if (t < 64) {
    float mx = -1e30f;
    for (int j = 0; j < NC; j++) mx = fmaxf(mx, Lb[t * 69 + j]);
    float s = 0.f;
    for (int j = 0; j < NC; j++) s += __expf(Lb[t * 69 + j] - mx);
    smax[t] = mx;
    slog[t] = __logf(s);
  }
  __syncthreads();

  for (int it = 0; it < 16; it++) {
    int idx = it * 256 + t;
    int r = idx >> 6;
    int c = idx & 63;
    int gr = row0 + r;
    if (gr < NN) out[(size_t)gr * NC + c] = Lb[r * 69 + c] - smax[r] - slog[r];
  }
}

// ---------------- launch ----------------
extern "C" void kernel_launch(void* const* d_in, const int* in_sizes, int n_in,
                              void* d_out, int out_size, void* d_ws, size_t ws_size,
                              hipStream_t stream) {
  const float* x      = (const float*)d_in[0];
  const int*   ei     = (const int*)d_in[1];
  const float* conv_w = (const float*)d_in[3];
  const float* conv_b = (const float*)d_in[4];
  const float* bn_g   = (const float*)d_in[5];
  const float* bn_b   = (const float*)d_in[6];
  const float* bn_m   = (const float*)d_in[7];
  const float* bn_v   = (const float*)d_in[8];
  const float* fc_w   = (const float*)d_in[9];
  const float* fc_b   = (const float*)d_in[10];
  float* out = (float*)d_out;

  const int* srcI = ei;        // edge_index[0]
  const int* dstI = ei + NE;   // edge_index[1]

  // workspace layout (~105 MiB)
  float* Abuf = (float*)d_ws;                       // N*H fp32
  float* Bbuf = Abuf + (size_t)NN * HF;             // N*H fp32
  int* cnt    = (int*)(Bbuf + (size_t)NN * HF);     // N
  int* offs   = cnt + 100000;                       // N+1 (padded to 100004)
  int* cursor = offs + 100004;                      // N
  int* bsums  = cursor + 100000;                    // 64
  int* csr    = bsums + 64;                         // E
  unsigned short* wt  = (unsigned short*)(csr + NE);  // 6*128*128 bf16 (W^T)
  unsigned short* wtf = wt + 6 * HF * HF;             // 64*128 bf16 (fc W^T)
  float* sarr = (float*)(wtf + HF * NC);              // 6*128
  float* tarr = sarr + 6 * HF;                        // 6*128

  hipMemsetAsync(cnt, 0, sizeof(int) * NN, stream);
  prep_weights<<<384, 256, 0, stream>>>(conv_w, conv_b, bn_g, bn_b, bn_m, bn_v, fc_w,
                                        wt, wtf, sarr, tarr);
  count_deg<<<NE / 256, 256, 0, stream>>>(dstI, cnt);
  scan_partial<<<NSB, 256, 0, stream>>>(cnt, bsums);
  scan_bsums<<<1, 64, 0, stream>>>(bsums, offs);
  scan_write<<<NSB, 256, 0, stream>>>(cnt, bsums, offs, cursor);
  scatter_edges<<<NE / 256, 256, 0, stream>>>(srcI, dstI, cursor, csr);

  aggregate<<<NN / 4, 256, 0, stream>>>(x, offs, csr, Abuf);
  mlp3<<<(NN + 63) / 64, 256, 0, stream>>>(Abuf, Bbuf, wt, sarr, tarr, 0);
  aggregate<<<NN / 4, 256, 0, stream>>>(Bbuf, offs, csr, Abuf);
  mlp3<<<(NN + 63) / 64, 256, 0, stream>>>(Abuf, Bbuf, wt, sarr, tarr, 1);
  fc_lsm<<<(NN + 63) / 64, 256, 0, stream>>>(Bbuf, wtf, fc_b, out);
}

// Round 2
// 517.888 us; speedup vs baseline: 1.4370x; 1.4370x over previous
//
#include <hip/hip_runtime.h>

#define NN 100000
#define NE 1600000
#define HF 128
#define NC 64
#define AP 136      // padded LDS row (bf16 elems): 272B stride, 16B-aligned chunks
#define NSB 49      // scan blocks: ceil(100000/2048)

typedef __bf16 bf16x8 __attribute__((ext_vector_type(8)));
typedef float  f32x4  __attribute__((ext_vector_type(4)));
typedef unsigned short us8 __attribute__((ext_vector_type(8)));

__device__ __forceinline__ unsigned short f2b(float x) {
  unsigned int u = __float_as_uint(x);
  u += 0x7FFFu + ((u >> 16) & 1u);   // RNE
  return (unsigned short)(u >> 16);
}
__device__ __forceinline__ float b2f(unsigned short b) {
  return __uint_as_float(((unsigned int)b) << 16);
}

// ---------------- weight prep: bf16 W^T + folded BN affine ----------------
__global__ void prep_weights(const float* __restrict__ conv_w, const float* __restrict__ conv_b,
                             const float* __restrict__ bn_g, const float* __restrict__ bn_b,
                             const float* __restrict__ bn_m, const float* __restrict__ bn_v,
                             const float* __restrict__ fc_w,
                             unsigned short* __restrict__ wt, unsigned short* __restrict__ wtf,
                             float* __restrict__ sarr, float* __restrict__ tarr) {
  int idx = blockIdx.x * 256 + threadIdx.x;
  if (idx < 6 * HF * HF) {
    int ls = idx / (HF * HF);
    int rem = idx - ls * HF * HF;
    int k = rem >> 7;          // input feature
    int n = rem & 127;         // output feature
    wt[(ls * HF + n) * HF + k] = f2b(conv_w[idx]);   // store W^T: [n][k]
  }
  if (idx < HF * NC) {
    int k = idx >> 6;
    int c = idx & 63;
    wtf[c * HF + k] = f2b(fc_w[idx]);                // fc W^T: [c][k]
  }
  if (idx < 6 * HF) {
    float s = bn_g[idx] * rsqrtf(bn_v[idx] + 1e-5f);
    sarr[idx] = s;
    tarr[idx] = (conv_b[idx] - bn_m[idx]) * s + bn_b[idx];  // fold linear bias into BN shift
  }
}

// ---------------- cast x fp32 -> bf16 ----------------
__global__ __launch_bounds__(256) void cast_bf16(const float* __restrict__ x,
                                                 unsigned short* __restrict__ xb) {
  size_t i = (size_t)(blockIdx.x * 256 + threadIdx.x) * 8;   // 12.8M elems / 8 = 1.6M threads
  float4 a = *(const float4*)(x + i);
  float4 b = *(const float4*)(x + i + 4);
  us8 v = { f2b(a.x), f2b(a.y), f2b(a.z), f2b(a.w),
            f2b(b.x), f2b(b.y), f2b(b.z), f2b(b.w) };
  *(us8*)(xb + i) = v;
}

// ---------------- CSR build ----------------
__global__ void count_deg(const int* __restrict__ dst, int* __restrict__ cnt) {
  int e = blockIdx.x * 256 + threadIdx.x;
  if (e < NE) atomicAdd(&cnt[dst[e]], 1);
}

__global__ void scan_partial(const int* __restrict__ cnt, int* __restrict__ bsums) {
  __shared__ int sm[256];
  int base = blockIdx.x * 2048;
  int t = threadIdx.x;
  int s = 0;
  for (int j = 0; j < 8; j++) {
    int i = base + t * 8 + j;
    if (i < NN) s += cnt[i];
  }
  sm[t] = s; __syncthreads();
  for (int off = 128; off > 0; off >>= 1) {
    if (t < off) sm[t] += sm[t + off];
    __syncthreads();
  }
  if (t == 0) bsums[blockIdx.x] = sm[0];
}

__global__ void scan_bsums(int* __restrict__ bsums, int* __restrict__ offs) {
  if (threadIdx.x == 0) {
    int acc = 0;
    for (int i = 0; i < NSB; i++) { int v = bsums[i]; bsums[i] = acc; acc += v; }
    bsums[NSB] = acc;
    offs[NN] = acc;    // == NE
  }
}

__global__ void scan_write(const int* __restrict__ cnt, const int* __restrict__ bsums,
                           int* __restrict__ offs, int* __restrict__ cursor) {
  __shared__ int sm[256];
  int base = blockIdx.x * 2048;
  int t = threadIdx.x;
  int loc[8];
  int s = 0;
  for (int j = 0; j < 8; j++) {
    int i = base + t * 8 + j;
    int v = (i < NN) ? cnt[i] : 0;
    loc[j] = s; s += v;
  }
  sm[t] = s; __syncthreads();
  for (int off = 1; off < 256; off <<= 1) {
    int v2 = (t >= off) ? sm[t - off] : 0;
    __syncthreads();
    sm[t] += v2;
    __syncthreads();
  }
  int thread_excl = sm[t] - s;
  int b = bsums[blockIdx.x];
  for (int j = 0; j < 8; j++) {
    int i = base + t * 8 + j;
    if (i < NN) { int o = b + thread_excl + loc[j]; offs[i] = o; cursor[i] = o; }
  }
}

__global__ void scatter_edges(const int* __restrict__ src, const int* __restrict__ dst,
                              int* __restrict__ cursor, int* __restrict__ csr) {
  int e = blockIdx.x * 256 + threadIdx.x;
  if (e < NE) {
    int p = atomicAdd(&cursor[dst[e]], 1);
    csr[p] = src[e];
  }
}

// ---------------- aggregation: hsum[i] = h[i] + sum_{e->i} h[src_e]  (bf16 in/out) ----
// One wave per node; 4 edge-streams (quarter-waves) of 16 lanes x 16B (us8) each.
__global__ __launch_bounds__(256) void aggregate(const unsigned short* __restrict__ h,
                                                 const int* __restrict__ offs,
                                                 const int* __restrict__ csr,
                                                 unsigned short* __restrict__ out) {
  int wave = threadIdx.x >> 6;
  int lane = threadIdx.x & 63;
  int node = blockIdx.x * 4 + wave;
  if (node >= NN) return;
  int g  = lane >> 4;     // edge group 0..3
  int sl = lane & 15;     // 16B column chunk
  int beg = offs[node], end = offs[node + 1];

  float acc[8];
  if (g == 0) {           // self contribution counted once
    us8 v = *(const us8*)(h + (size_t)node * HF + sl * 8);
    #pragma unroll
    for (int i = 0; i < 8; i++) acc[i] = b2f(v[i]);
  } else {
    #pragma unroll
    for (int i = 0; i < 8; i++) acc[i] = 0.f;
  }

  for (int e = beg + g; e < end; e += 4) {
    int s = csr[e];
    us8 v = *(const us8*)(h + (size_t)s * HF + sl * 8);
    #pragma unroll
    for (int i = 0; i < 8; i++) acc[i] += b2f(v[i]);
  }

  // reduce the 4 quarter-wave partials (lanes l, l^16, l^32, l^48)
  #pragma unroll
  for (int i = 0; i < 8; i++) {
    acc[i] += __shfl_xor(acc[i], 16, 64);
    acc[i] += __shfl_xor(acc[i], 32, 64);
  }
  if (g == 0) {
    us8 r;
    #pragma unroll
    for (int i = 0; i < 8; i++) r[i] = f2b(acc[i]);
    *(us8*)(out + (size_t)node * HF + sl * 8) = r;
  }
}

// ---------------- fused 3x (Linear->BN->ReLU) via MFMA bf16 (bf16 in/out) -------------
__global__ __launch_bounds__(256) void mlp3(const unsigned short* __restrict__ in,
                                            unsigned short* __restrict__ out,
                                            const unsigned short* __restrict__ wt,
                                            const float* __restrict__ sarr, const float* __restrict__ tarr,
                                            int layer) {
  __shared__ unsigned short Ab[64 * AP];   // activation tile, bf16
  __shared__ unsigned short Wb[HF * AP];   // W^T tile, bf16
  int t = threadIdx.x;
  int lane = t & 63, wave = t >> 6;
  int row0 = blockIdx.x * 64;

  // stage input tile (bf16, plain 16B copies)
  for (int it = 0; it < 4; it++) {
    int idx = it * 256 + t;          // 64 rows x 16 chunks
    int r = idx >> 4;
    int c = (idx & 15) << 3;
    int gr = row0 + r;
    us8 v = (us8)(0);
    if (gr < NN) v = *(const us8*)(in + (size_t)gr * HF + c);
    *(us8*)&Ab[r * AP + c] = v;
  }

  int m = lane & 15, q = lane >> 4;
  const unsigned short* wbase = wt + layer * 3 * HF * HF;

  for (int sub = 0; sub < 3; sub++) {
    __syncthreads();                        // Ab ready / prev Wb readers done
    const unsigned short* wsub = wbase + sub * HF * HF;
    for (int it = 0; it < 8; it++) {
      int idx = it * 256 + t;               // 128 rows x 16 chunks
      int r = idx >> 4;
      int c = (idx & 15) << 3;
      *(us8*)&Wb[r * AP + c] = *(const us8*)(wsub + r * HF + c);
    }
    __syncthreads();                        // Wb ready

    bf16x8 af[4];
    #pragma unroll
    for (int k0 = 0; k0 < 4; k0++)
      af[k0] = *(const bf16x8*)&Ab[(wave * 16 + m) * AP + k0 * 32 + q * 8];

    f32x4 acc[8];
    #pragma unroll
    for (int nt = 0; nt < 8; nt++) {
      acc[nt] = (f32x4){0.f, 0.f, 0.f, 0.f};
      #pragma unroll
      for (int k0 = 0; k0 < 4; k0++) {
        bf16x8 bf = *(const bf16x8*)&Wb[(nt * 16 + m) * AP + k0 * 32 + q * 8];
        acc[nt] = __builtin_amdgcn_mfma_f32_16x16x32_bf16(af[k0], bf, acc[nt], 0, 0, 0);
      }
    }
    __syncthreads();                        // all MFMA reads of Ab done before overwrite

    const float* sp = sarr + (layer * 3 + sub) * HF;
    const float* tp = tarr + (layer * 3 + sub) * HF;
    #pragma unroll
    for (int nt = 0; nt < 8; nt++) {
      int c = nt * 16 + m;
      float sc = sp[c], sh = tp[c];
      #pragma unroll
      for (int i = 0; i < 4; i++) {
        int r = wave * 16 + q * 4 + i;     // C/D layout: col=lane&15, row=(lane>>4)*4+i
        float y = fmaxf(acc[nt][i] * sc + sh, 0.f);
        Ab[r * AP + c] = f2b(y);
      }
    }
  }
  __syncthreads();
  // coalesced bf16 store of final tile
  for (int it = 0; it < 4; it++) {
    int idx = it * 256 + t;
    int r = idx >> 4;
    int c = (idx & 15) << 3;
    int gr = row0 + r;
    if (gr < NN) *(us8*)(out + (size_t)gr * HF + c) = *(const us8*)&Ab[r * AP + c];
  }
}

// ---------------- FC (128->64) + log_softmax (bf16 in, fp32 out) ----------------
__global__ __launch_bounds__(256) void fc_lsm(const unsigned short* __restrict__ h,
                                              const unsigned short* __restrict__ wtf,
                                              const float* __restrict__ fc_b,
                                              float* __restrict__ out) {
  __shared__ unsigned short Ab[64 * AP];
  __shared__ unsigned short Wb[NC * AP];
  __shared__ float Lb[64 * 69];
  __shared__ float smax[64], slog[64];
  int t = threadIdx.x;
  int lane = t & 63, wave = t >> 6;
  int row0 = blockIdx.x * 64;

  for (int it = 0; it < 4; it++) {
    int idx = it * 256 + t;
    int r = idx >> 4;
    int c = (idx & 15) << 3;
    int gr = row0 + r;
    us8 v = (us8)(0);
    if (gr < NN) v = *(const us8*)(h + (size_t)gr * HF + c);
    *(us8*)&Ab[r * AP + c] = v;
  }
  for (int it = 0; it < 4; it++) {
    int idx = it * 256 + t;                // 64 rows x 16 chunks
    int r = idx >> 4;
    int c = (idx & 15) << 3;
    *(us8*)&Wb[r * AP + c] = *(const us8*)(wtf + r * HF + c);
  }
  __syncthreads();

  int m = lane & 15, q = lane >> 4;
  bf16x8 af[4];
  #pragma unroll
  for (int k0 = 0; k0 < 4; k0++)
    af[k0] = *(const bf16x8*)&Ab[(wave * 16 + m) * AP + k0 * 32 + q * 8];

  f32x4 acc[4];
  #pragma unroll
  for (int nt = 0; nt < 4; nt++) {
    acc[nt] = (f32x4){0.f, 0.f, 0.f, 0.f};
    #pragma unroll
    for (int k0 = 0; k0 < 4; k0++) {
      bf16x8 bf = *(const bf16x8*)&Wb[(nt * 16 + m) * AP + k0 * 8 * 4 + q * 8];
      acc[nt] = __builtin_amdgcn_mfma_f32_16x16x32_bf16(af[k0], bf, acc[nt], 0, 0, 0);
    }
  }
  #pragma unroll
  for (int nt = 0; nt < 4; nt++) {
    int c = nt * 16 + m;
    float b = fc_b[c];
    #pragma unroll
    for (int i = 0; i < 4; i++)
      Lb[(wave * 16 + q * 4 + i) * 69 + c] = acc[nt][i] + b;
  }
  __syncthreads();

  if (t < 64) {
    float mx = -1e30f;
    for (int j = 0; j < NC; j++) mx = fmaxf(mx, Lb[t * 69 + j]);
    float s = 0.f;
    for (int j = 0; j < NC; j++) s += __expf(Lb[t * 69 + j] - mx);
    smax[t] = mx;
    slog[t] = __logf(s);
  }
  __syncthreads();

  for (int it = 0; it < 16; it++) {
    int idx = it * 256 + t;
    int r = idx >> 6;
    int c = idx & 63;
    int gr = row0 + r;
    if (gr < NN) out[(size_t)gr * NC + c] = Lb[r * 69 + c] - smax[r] - slog[r];
  }
}

// ---------------- launch ----------------
extern "C" void kernel_launch(void* const* d_in, const int* in_sizes, int n_in,
                              void* d_out, int out_size, void* d_ws, size_t ws_size,
                              hipStream_t stream) {
  const float* x      = (const float*)d_in[0];
  const int*   ei     = (const int*)d_in[1];
  const float* conv_w = (const float*)d_in[3];
  const float* conv_b = (const float*)d_in[4];
  const float* bn_g   = (const float*)d_in[5];
  const float* bn_b   = (const float*)d_in[6];
  const float* bn_m   = (const float*)d_in[7];
  const float* bn_v   = (const float*)d_in[8];
  const float* fc_w   = (const float*)d_in[9];
  const float* fc_b   = (const float*)d_in[10];
  float* out = (float*)d_out;

  const int* srcI = ei;        // edge_index[0]
  const int* dstI = ei + NE;   // edge_index[1]

  // workspace layout (~85 MiB)
  unsigned short* Xb   = (unsigned short*)d_ws;          // N*H bf16
  unsigned short* Abuf = Xb + (size_t)NN * HF;           // N*H bf16
  unsigned short* Bbuf = Abuf + (size_t)NN * HF;         // N*H bf16
  int* cnt    = (int*)(Bbuf + (size_t)NN * HF);          // N
  int* offs   = cnt + 100000;                            // N+1 (padded)
  int* cursor = offs + 100004;                           // N
  int* bsums  = cursor + 100000;                         // 64
  int* csr    = bsums + 64;                              // E
  unsigned short* wt  = (unsigned short*)(csr + NE);     // 6*128*128 bf16 (W^T)
  unsigned short* wtf = wt + 6 * HF * HF;                // 64*128 bf16 (fc W^T)
  float* sarr = (float*)(wtf + HF * NC);                 // 6*128
  float* tarr = sarr + 6 * HF;                           // 6*128

  hipMemsetAsync(cnt, 0, sizeof(int) * NN, stream);
  prep_weights<<<384, 256, 0, stream>>>(conv_w, conv_b, bn_g, bn_b, bn_m, bn_v, fc_w,
                                        wt, wtf, sarr, tarr);
  cast_bf16<<<6250, 256, 0, stream>>>(x, Xb);
  count_deg<<<NE / 256, 256, 0, stream>>>(dstI, cnt);
  scan_partial<<<NSB, 256, 0, stream>>>(cnt, bsums);
  scan_bsums<<<1, 64, 0, stream>>>(bsums, offs);
  scan_write<<<NSB, 256, 0, stream>>>(cnt, bsums, offs, cursor);
  scatter_edges<<<NE / 256, 256, 0, stream>>>(srcI, dstI, cursor, csr);

  aggregate<<<NN / 4, 256, 0, stream>>>(Xb, offs, csr, Abuf);
  mlp3<<<(NN + 63) / 64, 256, 0, stream>>>(Abuf, Bbuf, wt, sarr, tarr, 0);
  aggregate<<<NN / 4, 256, 0, stream>>>(Bbuf, offs, csr, Abuf);
  mlp3<<<(NN + 63) / 64, 256, 0, stream>>>(Abuf, Bbuf, wt, sarr, tarr, 1);
  fc_lsm<<<(NN + 63) / 64, 256, 0, stream>>>(Bbuf, wtf, fc_b, out);
}

// Round 3
// 410.113 us; speedup vs baseline: 1.8146x; 1.2628x over previous
//
#include <hip/hip_runtime.h>

#define NN 100000
#define NE 1600000
#define HF 128
#define NC 64
#define AP 136      // padded LDS row (bf16 elems): 272B stride, 16B-aligned chunks
#define NB 196      // edge buckets: ceil(100000/512)
#define BSH 9       // 512 nodes per bucket
#define BMASK 511

typedef __bf16 bf16x8 __attribute__((ext_vector_type(8)));
typedef float  f32x4  __attribute__((ext_vector_type(4)));
typedef unsigned short us8 __attribute__((ext_vector_type(8)));

__device__ __forceinline__ unsigned short f2b(float x) {
  unsigned int u = __float_as_uint(x);
  u += 0x7FFFu + ((u >> 16) & 1u);   // RNE
  return (unsigned short)(u >> 16);
}
__device__ __forceinline__ float b2f(unsigned short b) {
  return __uint_as_float(((unsigned int)b) << 16);
}

// ---------------- weight prep: bf16 W^T + folded BN affine ----------------
__global__ void prep_weights(const float* __restrict__ conv_w, const float* __restrict__ conv_b,
                             const float* __restrict__ bn_g, const float* __restrict__ bn_b,
                             const float* __restrict__ bn_m, const float* __restrict__ bn_v,
                             const float* __restrict__ fc_w,
                             unsigned short* __restrict__ wt, unsigned short* __restrict__ wtf,
                             float* __restrict__ sarr, float* __restrict__ tarr) {
  int idx = blockIdx.x * 256 + threadIdx.x;
  if (idx < 6 * HF * HF) {
    int ls = idx / (HF * HF);
    int rem = idx - ls * HF * HF;
    int k = rem >> 7;          // input feature
    int n = rem & 127;         // output feature
    wt[(ls * HF + n) * HF + k] = f2b(conv_w[idx]);   // store W^T: [n][k]
  }
  if (idx < HF * NC) {
    int k = idx >> 6;
    int c = idx & 63;
    wtf[c * HF + k] = f2b(fc_w[idx]);                // fc W^T: [c][k]
  }
  if (idx < 6 * HF) {
    float s = bn_g[idx] * rsqrtf(bn_v[idx] + 1e-5f);
    sarr[idx] = s;
    tarr[idx] = (conv_b[idx] - bn_m[idx]) * s + bn_b[idx];  // fold linear bias into BN shift
  }
}

// ---------------- cast x fp32 -> bf16 ----------------
__global__ __launch_bounds__(256) void cast_bf16(const float* __restrict__ x,
                                                 unsigned short* __restrict__ xb) {
  size_t i = (size_t)(blockIdx.x * 256 + threadIdx.x) * 8;
  float4 a = *(const float4*)(x + i);
  float4 b = *(const float4*)(x + i + 4);
  us8 v = { f2b(a.x), f2b(a.y), f2b(a.z), f2b(a.w),
            f2b(b.x), f2b(b.y), f2b(b.z), f2b(b.w) };
  *(us8*)(xb + i) = v;
}

// ---------------- bucket count: 196 buckets of 512 dst nodes ----------------
__global__ __launch_bounds__(256) void bcount(const int* __restrict__ dst,
                                              int* __restrict__ bcnt) {
  __shared__ int hist[NB];
  int t = threadIdx.x;
  if (t < NB) hist[t] = 0;
  __syncthreads();
  int base = blockIdx.x * 8192;
  for (int j = 0; j < 32; j++) {
    int e = base + j * 256 + t;
    if (e < NE) atomicAdd(&hist[dst[e] >> BSH], 1);
  }
  __syncthreads();
  if (t < NB && hist[t]) atomicAdd(&bcnt[t], hist[t]);
}

// ---------------- bucket scan (single block) ----------------
__global__ void bscan(const int* __restrict__ bcnt, int* __restrict__ bboffs,
                      int* __restrict__ gcur, int* __restrict__ offs) {
  __shared__ int sm[256];
  int t = threadIdx.x;
  int v = (t < NB) ? bcnt[t] : 0;
  sm[t] = v; __syncthreads();
  for (int off = 1; off < 256; off <<= 1) {
    int u = (t >= off) ? sm[t - off] : 0;
    __syncthreads();
    sm[t] += u;
    __syncthreads();
  }
  if (t < NB) { int ex = sm[t] - v; bboffs[t] = ex; gcur[t] = ex; }
  if (t == 0) { bboffs[NB] = NE; offs[NN] = NE; }
}

// ---------------- bin edges into bucket-grouped packed entries ----------------
// entry = src (17 bits) | dst_local (9 bits) << 17
__global__ __launch_bounds__(256) void bin_edges(const int* __restrict__ src,
                                                 const int* __restrict__ dst,
                                                 int* __restrict__ gcur,
                                                 unsigned int* __restrict__ binned) {
  __shared__ int hist[NB];
  int t = threadIdx.x;
  if (t < NB) hist[t] = 0;
  __syncthreads();
  int base = blockIdx.x * 8192;
  for (int j = 0; j < 32; j++) {
    int e = base + j * 256 + t;
    if (e < NE) atomicAdd(&hist[dst[e] >> BSH], 1);
  }
  __syncthreads();
  if (t < NB) {                       // reserve contiguous global range per bucket
    int c = hist[t];
    if (c) hist[t] = atomicAdd(&gcur[t], c);
  }
  __syncthreads();
  for (int j = 0; j < 32; j++) {
    int e = base + j * 256 + t;
    if (e < NE) {
      int d = dst[e];
      int b = d >> BSH;
      int p = atomicAdd(&hist[b], 1);
      binned[p] = (unsigned int)src[e] | ((unsigned int)(d & BMASK) << 17);
    }
  }
}

// ---------------- per-bucket CSR build: offs (coalesced) + csr (L2-local) ----
__global__ __launch_bounds__(256) void build_csr(const unsigned int* __restrict__ binned,
                                                 const int* __restrict__ bboffs,
                                                 int* __restrict__ offs,
                                                 int* __restrict__ csr) {
  __shared__ int ncnt[512];
  __shared__ int sm[256];
  int t = threadIdx.x;
  int b = blockIdx.x;
  int beg = bboffs[b], end = bboffs[b + 1];
  ncnt[t] = 0; ncnt[t + 256] = 0;
  __syncthreads();
  for (int e = beg + t; e < end; e += 256) atomicAdd(&ncnt[binned[e] >> 17], 1);
  __syncthreads();
  int c0 = ncnt[2 * t], c1 = ncnt[2 * t + 1];
  int s = c0 + c1;
  sm[t] = s; __syncthreads();
  for (int off = 1; off < 256; off <<= 1) {
    int u = (t >= off) ? sm[t - off] : 0;
    __syncthreads();
    sm[t] += u;
    __syncthreads();
  }
  int ex = sm[t] - s + beg;               // global csr position of node 2t in bucket
  int node0 = (b << BSH) + 2 * t;
  if (node0 < NN)     offs[node0]     = ex;
  if (node0 + 1 < NN) offs[node0 + 1] = ex + c0;
  ncnt[2 * t]     = ex;                   // reuse as global cursors
  ncnt[2 * t + 1] = ex + c0;
  __syncthreads();
  for (int e = beg + t; e < end; e += 256) {
    unsigned int u = binned[e];
    int p = atomicAdd(&ncnt[u >> 17], 1);
    csr[p] = (int)(u & 0x1FFFFu);
  }
}

// ---------------- aggregation: hsum[i] = h[i] + sum_{e->i} h[src_e]  (bf16) ----
__global__ __launch_bounds__(256) void aggregate(const unsigned short* __restrict__ h,
                                                 const int* __restrict__ offs,
                                                 const int* __restrict__ csr,
                                                 unsigned short* __restrict__ out) {
  int wave = threadIdx.x >> 6;
  int lane = threadIdx.x & 63;
  int node = blockIdx.x * 4 + wave;
  if (node >= NN) return;
  int g  = lane >> 4;     // edge group 0..3
  int sl = lane & 15;     // 16B column chunk
  int beg = offs[node], end = offs[node + 1];

  float acc[8];
  if (g == 0) {           // self contribution counted once
    us8 v = *(const us8*)(h + (size_t)node * HF + sl * 8);
    #pragma unroll
    for (int i = 0; i < 8; i++) acc[i] = b2f(v[i]);
  } else {
    #pragma unroll
    for (int i = 0; i < 8; i++) acc[i] = 0.f;
  }

  for (int e = beg + g; e < end; e += 4) {
    int s = csr[e];
    us8 v = *(const us8*)(h + (size_t)s * HF + sl * 8);
    #pragma unroll
    for (int i = 0; i < 8; i++) acc[i] += b2f(v[i]);
  }

  #pragma unroll
  for (int i = 0; i < 8; i++) {
    acc[i] += __shfl_xor(acc[i], 16, 64);
    acc[i] += __shfl_xor(acc[i], 32, 64);
  }
  if (g == 0) {
    us8 r;
    #pragma unroll
    for (int i = 0; i < 8; i++) r[i] = f2b(acc[i]);
    *(us8*)(out + (size_t)node * HF + sl * 8) = r;
  }
}

// ---------------- fused 3x (Linear->BN->ReLU) via MFMA bf16 ----------------
__global__ __launch_bounds__(256) void mlp3(const unsigned short* __restrict__ in,
                                            unsigned short* __restrict__ out,
                                            const unsigned short* __restrict__ wt,
                                            const float* __restrict__ sarr, const float* __restrict__ tarr,
                                            int layer) {
  __shared__ unsigned short Ab[64 * AP];
  __shared__ unsigned short Wb[HF * AP];
  int t = threadIdx.x;
  int lane = t & 63, wave = t >> 6;
  int row0 = blockIdx.x * 64;

  for (int it = 0; it < 4; it++) {
    int idx = it * 256 + t;
    int r = idx >> 4;
    int c = (idx & 15) << 3;
    int gr = row0 + r;
    us8 v = (us8)(0);
    if (gr < NN) v = *(const us8*)(in + (size_t)gr * HF + c);
    *(us8*)&Ab[r * AP + c] = v;
  }

  int m = lane & 15, q = lane >> 4;
  const unsigned short* wbase = wt + layer * 3 * HF * HF;

  for (int sub = 0; sub < 3; sub++) {
    __syncthreads();
    const unsigned short* wsub = wbase + sub * HF * HF;
    for (int it = 0; it < 8; it++) {
      int idx = it * 256 + t;
      int r = idx >> 4;
      int c = (idx & 15) << 3;
      *(us8*)&Wb[r * AP + c] = *(const us8*)(wsub + r * HF + c);
    }
    __syncthreads();

    bf16x8 af[4];
    #pragma unroll
    for (int k0 = 0; k0 < 4; k0++)
      af[k0] = *(const bf16x8*)&Ab[(wave * 16 + m) * AP + k0 * 32 + q * 8];

    f32x4 acc[8];
    #pragma unroll
    for (int nt = 0; nt < 8; nt++) {
      acc[nt] = (f32x4){0.f, 0.f, 0.f, 0.f};
      #pragma unroll
      for (int k0 = 0; k0 < 4; k0++) {
        bf16x8 bf = *(const bf16x8*)&Wb[(nt * 16 + m) * AP + k0 * 32 + q * 8];
        acc[nt] = __builtin_amdgcn_mfma_f32_16x16x32_bf16(af[k0], bf, acc[nt], 0, 0, 0);
      }
    }
    __syncthreads();

    const float* sp = sarr + (layer * 3 + sub) * HF;
    const float* tp = tarr + (layer * 3 + sub) * HF;
    #pragma unroll
    for (int nt = 0; nt < 8; nt++) {
      int c = nt * 16 + m;
      float sc = sp[c], sh = tp[c];
      #pragma unroll
      for (int i = 0; i < 4; i++) {
        int r = wave * 16 + q * 4 + i;     // C/D: col=lane&15, row=(lane>>4)*4+i
        float y = fmaxf(acc[nt][i] * sc + sh, 0.f);
        Ab[r * AP + c] = f2b(y);
      }
    }
  }
  __syncthreads();
  for (int it = 0; it < 4; it++) {
    int idx = it * 256 + t;
    int r = idx >> 4;
    int c = (idx & 15) << 3;
    int gr = row0 + r;
    if (gr < NN) *(us8*)(out + (size_t)gr * HF + c) = *(const us8*)&Ab[r * AP + c];
  }
}

// ---------------- FC (128->64) + log_softmax (bf16 in, fp32 out) ----------------
__global__ __launch_bounds__(256) void fc_lsm(const unsigned short* __restrict__ h,
                                              const unsigned short* __restrict__ wtf,
                                              const float* __restrict__ fc_b,
                                              float* __restrict__ out) {
  __shared__ unsigned short Ab[64 * AP];
  __shared__ unsigned short Wb[NC * AP];
  __shared__ float Lb[64 * 69];
  __shared__ float smax[64], slog[64];
  int t = threadIdx.x;
  int lane = t & 63, wave = t >> 6;
  int row0 = blockIdx.x * 64;

  for (int it = 0; it < 4; it++) {
    int idx = it * 256 + t;
    int r = idx >> 4;
    int c = (idx & 15) << 3;
    int gr = row0 + r;
    us8 v = (us8)(0);
    if (gr < NN) v = *(const us8*)(h + (size_t)gr * HF + c);
    *(us8*)&Ab[r * AP + c] = v;
  }
  for (int it = 0; it < 4; it++) {
    int idx = it * 256 + t;
    int r = idx >> 4;
    int c = (idx & 15) << 3;
    *(us8*)&Wb[r * AP + c] = *(const us8*)(wtf + r * HF + c);
  }
  __syncthreads();

  int m = lane & 15, q = lane >> 4;
  bf16x8 af[4];
  #pragma unroll
  for (int k0 = 0; k0 < 4; k0++)
    af[k0] = *(const bf16x8*)&Ab[(wave * 16 + m) * AP + k0 * 32 + q * 8];

  f32x4 acc[4];
  #pragma unroll
  for (int nt = 0; nt < 4; nt++) {
    acc[nt] = (f32x4){0.f, 0.f, 0.f, 0.f};
    #pragma unroll
    for (int k0 = 0; k0 < 4; k0++) {
      bf16x8 bf = *(const bf16x8*)&Wb[(nt * 16 + m) * AP + k0 * 32 + q * 8];
      acc[nt] = __builtin_amdgcn_mfma_f32_16x16x32_bf16(af[k0], bf, acc[nt], 0, 0, 0);
    }
  }
  #pragma unroll
  for (int nt = 0; nt < 4; nt++) {
    int c = nt * 16 + m;
    float b = fc_b[c];
    #pragma unroll
    for (int i = 0; i < 4; i++)
      Lb[(wave * 16 + q * 4 + i) * 69 + c] = acc[nt][i] + b;
  }
  __syncthreads();

  if (t < 64) {
    float mx = -1e30f;
    for (int j = 0; j < NC; j++) mx = fmaxf(mx, Lb[t * 69 + j]);
    float s = 0.f;
    for (int j = 0; j < NC; j++) s += __expf(Lb[t * 69 + j] - mx);
    smax[t] = mx;
    slog[t] = __logf(s);
  }
  __syncthreads();

  for (int it = 0; it < 16; it++) {
    int idx = it * 256 + t;
    int r = idx >> 6;
    int c = idx & 63;
    int gr = row0 + r;
    if (gr < NN) out[(size_t)gr * NC + c] = Lb[r * 69 + c] - smax[r] - slog[r];
  }
}

// ---------------- launch ----------------
extern "C" void kernel_launch(void* const* d_in, const int* in_sizes, int n_in,
                              void* d_out, int out_size, void* d_ws, size_t ws_size,
                              hipStream_t stream) {
  const float* x      = (const float*)d_in[0];
  const int*   ei     = (const int*)d_in[1];
  const float* conv_w = (const float*)d_in[3];
  const float* conv_b = (const float*)d_in[4];
  const float* bn_g   = (const float*)d_in[5];
  const float* bn_b   = (const float*)d_in[6];
  const float* bn_m   = (const float*)d_in[7];
  const float* bn_v   = (const float*)d_in[8];
  const float* fc_w   = (const float*)d_in[9];
  const float* fc_b   = (const float*)d_in[10];
  float* out = (float*)d_out;

  const int* srcI = ei;        // edge_index[0]
  const int* dstI = ei + NE;   // edge_index[1]

  // workspace layout (~90 MiB)
  unsigned short* Xb   = (unsigned short*)d_ws;          // N*H bf16
  unsigned short* Abuf = Xb + (size_t)NN * HF;           // N*H bf16
  unsigned short* Bbuf = Abuf + (size_t)NN * HF;         // N*H bf16
  int* bcnt   = (int*)(Bbuf + (size_t)NN * HF);          // 256
  int* bboffs = bcnt + 256;                              // 200
  int* gcur   = bboffs + 200;                            // 256
  int* offs   = gcur + 256;                              // N+4
  unsigned int* binned = (unsigned int*)(offs + 100004); // E
  int* csr    = (int*)(binned + NE);                     // E
  unsigned short* wt  = (unsigned short*)(csr + NE);     // 6*128*128 bf16
  unsigned short* wtf = wt + 6 * HF * HF;                // 64*128 bf16
  float* sarr = (float*)(wtf + HF * NC);                 // 6*128
  float* tarr = sarr + 6 * HF;                           // 6*128

  hipMemsetAsync(bcnt, 0, sizeof(int) * 256, stream);
  prep_weights<<<384, 256, 0, stream>>>(conv_w, conv_b, bn_g, bn_b, bn_m, bn_v, fc_w,
                                        wt, wtf, sarr, tarr);
  cast_bf16<<<6250, 256, 0, stream>>>(x, Xb);
  bcount<<<196, 256, 0, stream>>>(dstI, bcnt);
  bscan<<<1, 256, 0, stream>>>(bcnt, bboffs, gcur, offs);
  bin_edges<<<196, 256, 0, stream>>>(srcI, dstI, gcur, binned);
  build_csr<<<196, 256, 0, stream>>>(binned, bboffs, offs, csr);

  aggregate<<<NN / 4, 256, 0, stream>>>(Xb, offs, csr, Abuf);
  mlp3<<<(NN + 63) / 64, 256, 0, stream>>>(Abuf, Bbuf, wt, sarr, tarr, 0);
  aggregate<<<NN / 4, 256, 0, stream>>>(Bbuf, offs, csr, Abuf);
  mlp3<<<(NN + 63) / 64, 256, 0, stream>>>(Abuf, Bbuf, wt, sarr, tarr, 1);
  fc_lsm<<<(NN + 63) / 64, 256, 0, stream>>>(Bbuf, wtf, fc_b, out);
}